// Round 1
// baseline (1264.348 us; speedup 1.0000x reference)
//
#include <hip/hip_runtime.h>
#include <hip/hip_bf16.h>

#define B_ 2
#define L_ 2048
#define DIM_ 512
#define NH_ 8
#define HD_ 64
#define TOPK_ 512
#define SCALE_ 0.125f

__device__ __forceinline__ unsigned f2ord(float f) {
  unsigned u = __float_as_uint(f);
  return (u >> 31) ? ~u : (u | 0x80000000u);
}
__device__ __forceinline__ float ord2f(unsigned k) {
  unsigned u = (k >> 31) ? (k ^ 0x80000000u) : ~k;
  return __uint_as_float(u);
}

// out[m][n] = sum_k A[m][k]*Bw[n][k] + bias[n]
// EPI 0: plain row-major store. EPI 1: scatter to Q / K^T / V.
template<int BM, int BN, int BK, int TM, int TN, int EPI>
__global__ __launch_bounds__(256) void gemm_k(
    const float* __restrict__ A, const float* __restrict__ Bw,
    const float* __restrict__ bias, float* __restrict__ out,
    float* __restrict__ Qb, float* __restrict__ Ktb, float* __restrict__ Vb,
    int M, int N, int K)
{
  __shared__ float As[BK][BM];
  __shared__ float Bs[BK][BN];
  const int tid = threadIdx.x;
  const int m0 = blockIdx.y * BM;
  const int n0 = blockIdx.x * BN;
  constexpr int TX = BN / TN;
  const int tn = (tid % TX) * TN;
  const int tm = (tid / TX) * TM;

  float acc[TM][TN];
#pragma unroll
  for (int i = 0; i < TM; ++i)
#pragma unroll
    for (int j = 0; j < TN; ++j) acc[i][j] = 0.f;

  constexpr int A4 = BM * BK / 4;
  constexpr int B4 = BN * BK / 4;

  for (int k0 = 0; k0 < K; k0 += BK) {
    for (int idx = tid; idx < A4; idx += 256) {
      int e = idx * 4;
      int row = e / BK, col = e % BK;
      float4 v = *(const float4*)(A + (size_t)(m0 + row) * K + k0 + col);
      As[col][row] = v.x; As[col+1][row] = v.y; As[col+2][row] = v.z; As[col+3][row] = v.w;
    }
    for (int idx = tid; idx < B4; idx += 256) {
      int e = idx * 4;
      int row = e / BK, col = e % BK;
      float4 v = *(const float4*)(Bw + (size_t)(n0 + row) * K + k0 + col);
      Bs[col][row] = v.x; Bs[col+1][row] = v.y; Bs[col+2][row] = v.z; Bs[col+3][row] = v.w;
    }
    __syncthreads();
#pragma unroll
    for (int kk = 0; kk < BK; ++kk) {
      float a[TM], b[TN];
#pragma unroll
      for (int i = 0; i < TM; i += 4) *(float4*)&a[i] = *(const float4*)&As[kk][tm + i];
#pragma unroll
      for (int j = 0; j < TN; j += 4) *(float4*)&b[j] = *(const float4*)&Bs[kk][tn + j];
#pragma unroll
      for (int i = 0; i < TM; ++i)
#pragma unroll
        for (int j = 0; j < TN; ++j) acc[i][j] = fmaf(a[i], b[j], acc[i][j]);
    }
    __syncthreads();
  }

#pragma unroll
  for (int i = 0; i < TM; ++i) {
    const int m = m0 + tm + i;
#pragma unroll
    for (int j = 0; j < TN; ++j) {
      const int n = n0 + tn + j;
      const float v = acc[i][j] + bias[n];
      if (EPI == 0) {
        out[(size_t)m * N + n] = v;
      } else {
        const int b = m >> 11, l = m & (L_ - 1);
        const int which = n >> 9, h = (n >> 6) & (NH_ - 1), d = n & (HD_ - 1);
        const int bh = b * NH_ + h;
        if (which == 0)      Qb[((size_t)bh * L_ + l) * HD_ + d] = v;
        else if (which == 1) Ktb[((size_t)bh * HD_ + d) * L_ + l] = v;
        else                 Vb[((size_t)bh * L_ + l) * HD_ + d] = v;
      }
    }
  }
}

// One block = 8 query rows of one (b,h). 256 threads, 4 waves.
// Phase 1: scores into LDS (all threads). Phase 2+3: per-wave (2 rows each):
// exact top-512 threshold via 32-bit bisection on order-preserving uint keys
// cached in registers, compaction of (p, idx), then PV over 512 selected keys.
__global__ __launch_bounds__(256) void attn_k(
    const float* __restrict__ Qb, const float* __restrict__ Ktb,
    const float* __restrict__ Vb, float* __restrict__ AO)
{
  constexpr int QR = 8;
  __shared__ float sc[QR][L_];      // 64 KB: scores, then compacted p/idx
  __shared__ float qs[QR][HD_];     // 2 KB
  __shared__ float rowinv_s[QR];

  const int tid = threadIdx.x;
  const int lane = tid & 63;
  const int wid = tid >> 6;
  const int bh = blockIdx.x >> 8;            // blockIdx.x / (L_/QR)
  const int r0 = (blockIdx.x & 255) * QR;
  const float* __restrict__ qbase = Qb + ((size_t)bh * L_ + r0) * HD_;
  const float* __restrict__ kbase = Ktb + (size_t)bh * HD_ * L_;
  const float* __restrict__ vbase = Vb + (size_t)bh * L_ * HD_;

  for (int i = tid; i < QR * HD_; i += 256) qs[i >> 6][i & 63] = qbase[i];
  __syncthreads();

  // ---- Phase 1: scores. Each thread owns 4 keys per half (k in regs). ----
#pragma unroll 1
  for (int half = 0; half < 2; ++half) {
    const int jb = half * 1024 + tid;
    float accs[QR][4];
#pragma unroll
    for (int r = 0; r < QR; ++r)
#pragma unroll
      for (int kk = 0; kk < 4; ++kk) accs[r][kk] = 0.f;
#pragma unroll
    for (int dc = 0; dc < 4; ++dc) {         // d-chunks of 16
      float kv[4][16];
#pragma unroll
      for (int kk = 0; kk < 4; ++kk)
#pragma unroll
        for (int dd = 0; dd < 16; ++dd)
          kv[kk][dd] = kbase[(size_t)(dc * 16 + dd) * L_ + jb + kk * 256];
#pragma unroll
      for (int r = 0; r < QR; ++r) {
#pragma unroll
        for (int c = 0; c < 4; ++c) {
          const float4 q4 = *(const float4*)&qs[r][dc * 16 + c * 4];  // LDS broadcast
#pragma unroll
          for (int kk = 0; kk < 4; ++kk) {
            accs[r][kk] = fmaf(q4.x, kv[kk][c*4+0], accs[r][kk]);
            accs[r][kk] = fmaf(q4.y, kv[kk][c*4+1], accs[r][kk]);
            accs[r][kk] = fmaf(q4.z, kv[kk][c*4+2], accs[r][kk]);
            accs[r][kk] = fmaf(q4.w, kv[kk][c*4+3], accs[r][kk]);
          }
        }
      }
    }
#pragma unroll
    for (int r = 0; r < QR; ++r)
#pragma unroll
      for (int kk = 0; kk < 4; ++kk)
        sc[r][half * 1024 + kk * 256 + tid] = accs[r][kk] * SCALE_;
  }
  __syncthreads();

  // ---- Phase 2: per-wave exact top-512 selection + compaction ----
#pragma unroll 1
  for (int sub = 0; sub < 2; ++sub) {
    const int r = wid * 2 + sub;
    unsigned keys[32];
    float mx = -3.0e38f;
#pragma unroll
    for (int t = 0; t < 32; ++t) {
      const float s = sc[r][lane + 64 * t];
      keys[t] = f2ord(s);
      mx = fmaxf(mx, s);
    }
#pragma unroll
    for (int off = 32; off; off >>= 1) mx = fmaxf(mx, __shfl_xor(mx, off));

    // P = exact key of the 512th-largest score (bit bisection, uniform count)
    unsigned P = 0;
#pragma unroll 1
    for (int bit = 31; bit >= 0; --bit) {
      const unsigned cand = P | (1u << bit);
      int c = 0;
#pragma unroll
      for (int t = 0; t < 32; ++t)
        c += (int)__popcll(__ballot(keys[t] >= cand));
      if (c >= TOPK_) P = cand;
    }

    // compact (p, idx); ties at P: keep first 512 in ascending key-index order
    int base = 0;
    float part = 0.f;
#pragma unroll
    for (int t = 0; t < 32; ++t) {
      const bool sel = keys[t] >= P;
      const unsigned long long mb = __ballot(sel);
      const int pos = base + (int)__popcll(mb & ((1ull << lane) - 1ull));
      if (sel && pos < TOPK_) {
        const float p = __expf(ord2f(keys[t]) - mx);
        sc[r][pos] = p;
        sc[r][TOPK_ + pos] = __int_as_float(lane + 64 * t);
        part += p;
      }
      base += (int)__popcll(mb);
    }
#pragma unroll
    for (int off = 32; off; off >>= 1) part += __shfl_xor(part, off);
    if (lane == 0) rowinv_s[r] = 1.f / part;
  }
  __syncthreads();

  // ---- Phase 3: PV over the 512 selected keys. lane = output dim. ----
  const int b = bh >> 3, h = bh & 7;
#pragma unroll 1
  for (int sub = 0; sub < 2; ++sub) {
    const int r = wid * 2 + sub;
    const float inv = rowinv_s[r];
    float acc = 0.f;
#pragma unroll 4
    for (int kk = 0; kk < TOPK_; kk += 4) {
      const float4 p4 = *(const float4*)&sc[r][kk];          // LDS broadcast
      const float4 i4 = *(const float4*)&sc[r][TOPK_ + kk];  // idx bits
      acc = fmaf(p4.x, vbase[(size_t)__float_as_uint(i4.x) * HD_ + lane], acc);
      acc = fmaf(p4.y, vbase[(size_t)__float_as_uint(i4.y) * HD_ + lane], acc);
      acc = fmaf(p4.z, vbase[(size_t)__float_as_uint(i4.z) * HD_ + lane], acc);
      acc = fmaf(p4.w, vbase[(size_t)__float_as_uint(i4.w) * HD_ + lane], acc);
    }
    AO[((size_t)(b * L_ + r0 + r)) * DIM_ + h * HD_ + lane] = acc * inv;
  }
}

extern "C" void kernel_launch(void* const* d_in, const int* in_sizes, int n_in,
                              void* d_out, int out_size, void* d_ws, size_t ws_size,
                              hipStream_t stream) {
  const float* x     = (const float*)d_in[0];
  const float* w_qkv = (const float*)d_in[1];
  const float* b_qkv = (const float*)d_in[2];
  const float* w_out = (const float*)d_in[3];
  const float* b_out = (const float*)d_in[4];
  float* out = (float*)d_out;
  float* ws  = (float*)d_ws;

  const size_t NT = (size_t)B_ * NH_ * L_ * HD_;  // 2,097,152 floats
  float* Qb  = ws;             // [bh][l][64]
  float* Ktb = ws + NT;        // [bh][64][l]
  float* Vb  = ws + 2 * NT;    // [bh][l][64]
  float* AO  = ws + 3 * NT;    // [b][l][512]
  const int M = B_ * L_;       // 4096

  gemm_k<128,128,16,8,8,1><<<dim3((3*DIM_)/128, M/128), 256, 0, stream>>>(
      x, w_qkv, b_qkv, nullptr, Qb, Ktb, Vb, M, 3*DIM_, DIM_);
  attn_k<<<dim3(B_ * NH_ * (L_/8)), 256, 0, stream>>>(Qb, Ktb, Vb, AO);
  gemm_k<64,64,16,4,4,0><<<dim3(DIM_/64, M/64), 256, 0, stream>>>(
      AO, w_out, b_out, out, nullptr, nullptr, nullptr, M, DIM_, DIM_);
}

// Round 3
// 551.950 us; speedup vs baseline: 2.2907x; 2.2907x over previous
//
#include <hip/hip_runtime.h>
#include <hip/hip_bf16.h>

#define B_ 2
#define L_ 2048
#define DIM_ 512
#define NH_ 8
#define HD_ 64
#define TOPK_ 512
#define SCALE_ 0.125f

__device__ __forceinline__ unsigned f2ord(float f) {
  unsigned u = __float_as_uint(f);
  return (u >> 31) ? ~u : (u | 0x80000000u);
}
__device__ __forceinline__ float ord2f(unsigned k) {
  unsigned u = (k >> 31) ? (k ^ 0x80000000u) : ~k;
  return __uint_as_float(u);
}

// out[m][n] = sum_k A[m][k]*Bw[n][k] + bias[n]
// EPI 0: plain row-major store. EPI 1: scatter to Q / K^T / V.
template<int BM, int BN, int BK, int TM, int TN, int EPI>
__global__ __launch_bounds__(256) void gemm_k(
    const float* __restrict__ A, const float* __restrict__ Bw,
    const float* __restrict__ bias, float* __restrict__ out,
    float* __restrict__ Qb, float* __restrict__ Ktb, float* __restrict__ Vb,
    int M, int N, int K)
{
  __shared__ float As[BK][BM];
  __shared__ float Bs[BK][BN];
  const int tid = threadIdx.x;
  const int m0 = blockIdx.y * BM;
  const int n0 = blockIdx.x * BN;
  constexpr int TX = BN / TN;
  const int tn = (tid % TX) * TN;
  const int tm = (tid / TX) * TM;

  float acc[TM][TN];
#pragma unroll
  for (int i = 0; i < TM; ++i)
#pragma unroll
    for (int j = 0; j < TN; ++j) acc[i][j] = 0.f;

  constexpr int A4 = BM * BK / 4;
  constexpr int B4 = BN * BK / 4;

  for (int k0 = 0; k0 < K; k0 += BK) {
    for (int idx = tid; idx < A4; idx += 256) {
      int e = idx * 4;
      int row = e / BK, col = e % BK;
      float4 v = *(const float4*)(A + (size_t)(m0 + row) * K + k0 + col);
      As[col][row] = v.x; As[col+1][row] = v.y; As[col+2][row] = v.z; As[col+3][row] = v.w;
    }
    for (int idx = tid; idx < B4; idx += 256) {
      int e = idx * 4;
      int row = e / BK, col = e % BK;
      float4 v = *(const float4*)(Bw + (size_t)(n0 + row) * K + k0 + col);
      Bs[col][row] = v.x; Bs[col+1][row] = v.y; Bs[col+2][row] = v.z; Bs[col+3][row] = v.w;
    }
    __syncthreads();
#pragma unroll
    for (int kk = 0; kk < BK; ++kk) {
      float a[TM], b[TN];
#pragma unroll
      for (int i = 0; i < TM; i += 4) *(float4*)&a[i] = *(const float4*)&As[kk][tm + i];
#pragma unroll
      for (int j = 0; j < TN; j += 4) *(float4*)&b[j] = *(const float4*)&Bs[kk][tn + j];
#pragma unroll
      for (int i = 0; i < TM; ++i)
#pragma unroll
        for (int j = 0; j < TN; ++j) acc[i][j] = fmaf(a[i], b[j], acc[i][j]);
    }
    __syncthreads();
  }

#pragma unroll
  for (int i = 0; i < TM; ++i) {
    const int m = m0 + tm + i;
#pragma unroll
    for (int j = 0; j < TN; ++j) {
      const int n = n0 + tn + j;
      const float v = acc[i][j] + bias[n];
      if (EPI == 0) {
        out[(size_t)m * N + n] = v;
      } else {
        const int b = m >> 11, l = m & (L_ - 1);
        const int which = n >> 9, h = (n >> 6) & (NH_ - 1), d = n & (HD_ - 1);
        const int bh = b * NH_ + h;
        if (which == 0)      Qb[((size_t)bh * L_ + l) * HD_ + d] = v;
        else if (which == 1) Ktb[((size_t)bh * HD_ + d) * L_ + l] = v;
        else                 Vb[((size_t)bh * L_ + l) * HD_ + d] = v;
      }
    }
  }
}

// One block = 4 query rows of one (b,h). 256 threads, 4 waves.
// Phase 1 (block-wide): scores into LDS, thread owns 8 consecutive keys
// (float4 K loads). Phase 2+3 (one wave per row, no barriers): exact top-512
// via bit bisection on ordered uint keys, compaction, PV with 8 accumulators.
__global__ __launch_bounds__(256, 4) void attn_k(
    const float* __restrict__ Qb, const float* __restrict__ Ktb,
    const float* __restrict__ Vb, float* __restrict__ AO)
{
  constexpr int QR = 4;
  __shared__ float sc[QR][L_];      // 32 KB: scores, then compacted p/idx
  __shared__ float qs[QR][HD_];     // 1 KB

  const int tid = threadIdx.x;
  const int lane = tid & 63;
  const int wid = tid >> 6;
  const int bh = blockIdx.x >> 9;            // blockIdx.x / (L_/QR)
  const int r0 = (blockIdx.x & 511) * QR;
  const float* __restrict__ qbase = Qb + ((size_t)bh * L_ + r0) * HD_;
  const float* __restrict__ kbase = Ktb + (size_t)bh * HD_ * L_;
  const float* __restrict__ vbase = Vb + (size_t)bh * L_ * HD_;

  for (int i = tid; i < QR * HD_; i += 256) qs[i >> 6][i & 63] = qbase[i];
  __syncthreads();

  // ---- Phase 1: scores. Thread owns keys [8*tid, 8*tid+8). ----
  {
    float accs[QR][8];
#pragma unroll
    for (int r = 0; r < QR; ++r)
#pragma unroll
      for (int c = 0; c < 8; ++c) accs[r][c] = 0.f;

    const float* kp = kbase + 8 * tid;
#pragma unroll 4
    for (int d0 = 0; d0 < HD_; d0 += 4) {
      float ka[4][8];
#pragma unroll
      for (int dd = 0; dd < 4; ++dd) {
        *(float4*)&ka[dd][0] = *(const float4*)(kp + (size_t)(d0 + dd) * L_);
        *(float4*)&ka[dd][4] = *(const float4*)(kp + (size_t)(d0 + dd) * L_ + 4);
      }
#pragma unroll
      for (int r = 0; r < QR; ++r) {
        float qa[4];
        *(float4*)qa = *(const float4*)&qs[r][d0];   // LDS broadcast
#pragma unroll
        for (int dd = 0; dd < 4; ++dd)
#pragma unroll
          for (int c = 0; c < 8; ++c)
            accs[r][c] = fmaf(qa[dd], ka[dd][c], accs[r][c]);
      }
    }
#pragma unroll
    for (int r = 0; r < QR; ++r) {
      float4 lo = make_float4(accs[r][0]*SCALE_, accs[r][1]*SCALE_, accs[r][2]*SCALE_, accs[r][3]*SCALE_);
      float4 hi = make_float4(accs[r][4]*SCALE_, accs[r][5]*SCALE_, accs[r][6]*SCALE_, accs[r][7]*SCALE_);
      *(float4*)&sc[r][8 * tid] = lo;
      *(float4*)&sc[r][8 * tid + 4] = hi;
    }
  }
  __syncthreads();

  // ---- Phase 2: per-wave exact top-512 selection + compaction (row = wid) ----
  float inv;
  {
    unsigned keys[32];
    float mx = -3.0e38f;
#pragma unroll
    for (int t = 0; t < 32; ++t) {
      const float s = sc[wid][lane + 64 * t];
      keys[t] = f2ord(s);
      mx = fmaxf(mx, s);
    }
#pragma unroll
    for (int off = 32; off; off >>= 1) mx = fmaxf(mx, __shfl_xor(mx, off));

    unsigned P = 0;
#pragma unroll 1
    for (int bit = 31; bit >= 0; --bit) {
      const unsigned cand = P | (1u << bit);
      int c = 0;
#pragma unroll
      for (int t = 0; t < 32; ++t)
        c += (int)__popcll(__ballot(keys[t] >= cand));
      if (c >= TOPK_) P = cand;
    }

    // compact (p, idx); ties at P: keep first TOPK_ in ascending key-index order
    int base = 0;
    float part = 0.f;
#pragma unroll
    for (int t = 0; t < 32; ++t) {
      const bool sel = keys[t] >= P;
      const unsigned long long mb = __ballot(sel);
      const int pos = base + (int)__popcll(mb & ((1ull << lane) - 1ull));
      if (sel && pos < TOPK_) {
        const float p = __expf(ord2f(keys[t]) - mx);
        sc[wid][pos] = p;
        sc[wid][TOPK_ + pos] = __int_as_float(lane + 64 * t);
        part += p;
      }
      base += (int)__popcll(mb);
    }
#pragma unroll
    for (int off = 32; off; off >>= 1) part += __shfl_xor(part, off);
    inv = 1.f / part;
  }

  // ---- Phase 3: PV over the 512 selected keys (row = wid). lane = out dim. ----
  {
    const int b = bh >> 3, h = bh & 7;
    float acc[8];
#pragma unroll
    for (int c = 0; c < 8; ++c) acc[c] = 0.f;
#pragma unroll 2
    for (int kk = 0; kk < TOPK_; kk += 8) {
      float pa[8], ia[8];
      *(float4*)&pa[0] = *(const float4*)&sc[wid][kk];
      *(float4*)&pa[4] = *(const float4*)&sc[wid][kk + 4];
      *(float4*)&ia[0] = *(const float4*)&sc[wid][TOPK_ + kk];
      *(float4*)&ia[4] = *(const float4*)&sc[wid][TOPK_ + kk + 4];
#pragma unroll
      for (int c = 0; c < 8; ++c) {
        const size_t idx = (size_t)__float_as_uint(ia[c]);
        acc[c] = fmaf(pa[c], vbase[idx * HD_ + lane], acc[c]);
      }
    }
    const float r = (((acc[0] + acc[1]) + (acc[2] + acc[3])) +
                     ((acc[4] + acc[5]) + (acc[6] + acc[7]))) * inv;
    AO[((size_t)(b * L_ + r0 + wid)) * DIM_ + h * HD_ + lane] = r;
  }
}

extern "C" void kernel_launch(void* const* d_in, const int* in_sizes, int n_in,
                              void* d_out, int out_size, void* d_ws, size_t ws_size,
                              hipStream_t stream) {
  const float* x     = (const float*)d_in[0];
  const float* w_qkv = (const float*)d_in[1];
  const float* b_qkv = (const float*)d_in[2];
  const float* w_out = (const float*)d_in[3];
  const float* b_out = (const float*)d_in[4];
  float* out = (float*)d_out;
  float* ws  = (float*)d_ws;

  const size_t NT = (size_t)B_ * NH_ * L_ * HD_;  // 2,097,152 floats
  float* Qb  = ws;             // [bh][l][64]
  float* Ktb = ws + NT;        // [bh][64][l]
  float* Vb  = ws + 2 * NT;    // [bh][l][64]
  float* AO  = ws + 3 * NT;    // [b][l][512]
  const int M = B_ * L_;       // 4096

  gemm_k<128,128,16,8,8,1><<<dim3((3*DIM_)/128, M/128), 256, 0, stream>>>(
      x, w_qkv, b_qkv, nullptr, Qb, Ktb, Vb, M, 3*DIM_, DIM_);
  attn_k<<<dim3(B_ * NH_ * (L_/4)), 256, 0, stream>>>(Qb, Ktb, Vb, AO);
  gemm_k<64,64,16,4,4,0><<<dim3(DIM_/64, M/64), 256, 0, stream>>>(
      AO, w_out, b_out, out, nullptr, nullptr, nullptr, M, DIM_, DIM_);
}

// Round 4
// 510.844 us; speedup vs baseline: 2.4750x; 1.0805x over previous
//
#include <hip/hip_runtime.h>

#define B_ 2
#define L_ 2048
#define DIM_ 512
#define NH_ 8
#define HD_ 64
#define TOPK_ 512

typedef __attribute__((ext_vector_type(8))) short short8;
typedef __attribute__((ext_vector_type(4))) float f32x4;
typedef unsigned short ushort_t;

__device__ __forceinline__ unsigned f2ord(float f) {
  unsigned u = __float_as_uint(f);
  return (u >> 31) ? ~u : (u | 0x80000000u);
}
__device__ __forceinline__ float ord2f(unsigned k) {
  unsigned u = (k >> 31) ? (k ^ 0x80000000u) : ~k;
  return __uint_as_float(u);
}
// f32 -> bf16 bits, round-to-nearest-even
__device__ __forceinline__ ushort_t bfrne(float f) {
  unsigned u = __float_as_uint(f);
  return (ushort_t)((u + 0x7FFFu + ((u >> 16) & 1u)) >> 16);
}

// ---------------- QKV GEMM: x[4096x512] @ w_qkv^T[512x1536] + b ----------------
// Epilogue splits into bf16 hi/lo panels: Qh/Ql (x0.125 folded), Kh/Kl, and V^T bf16.
__global__ __launch_bounds__(256) void gemm_qkv(
    const float* __restrict__ A, const float* __restrict__ Bw,
    const float* __restrict__ bias,
    ushort_t* __restrict__ Qh, ushort_t* __restrict__ Ql,
    ushort_t* __restrict__ Kh, ushort_t* __restrict__ Kl,
    ushort_t* __restrict__ Vt)
{
  constexpr int BM = 128, BN = 128, BK = 16, TM = 8, TN = 8;
  const int M = B_ * L_, N = 3 * DIM_, K = DIM_;
  __shared__ float As[BK][BM];
  __shared__ float Bs[BK][BN];
  const int tid = threadIdx.x;
  const int m0 = blockIdx.y * BM;
  const int n0 = blockIdx.x * BN;
  constexpr int TX = BN / TN;
  const int tn = (tid % TX) * TN;
  const int tm = (tid / TX) * TM;

  float acc[TM][TN];
#pragma unroll
  for (int i = 0; i < TM; ++i)
#pragma unroll
    for (int j = 0; j < TN; ++j) acc[i][j] = 0.f;

  constexpr int A4 = BM * BK / 4;
  constexpr int B4 = BN * BK / 4;

  for (int k0 = 0; k0 < K; k0 += BK) {
    for (int idx = tid; idx < A4; idx += 256) {
      int e = idx * 4;
      int row = e / BK, col = e % BK;
      float4 v = *(const float4*)(A + (size_t)(m0 + row) * K + k0 + col);
      As[col][row] = v.x; As[col+1][row] = v.y; As[col+2][row] = v.z; As[col+3][row] = v.w;
    }
    for (int idx = tid; idx < B4; idx += 256) {
      int e = idx * 4;
      int row = e / BK, col = e % BK;
      float4 v = *(const float4*)(Bw + (size_t)(n0 + row) * K + k0 + col);
      Bs[col][row] = v.x; Bs[col+1][row] = v.y; Bs[col+2][row] = v.z; Bs[col+3][row] = v.w;
    }
    __syncthreads();
#pragma unroll
    for (int kk = 0; kk < BK; ++kk) {
      float a[TM], b[TN];
#pragma unroll
      for (int i = 0; i < TM; i += 4) *(float4*)&a[i] = *(const float4*)&As[kk][tm + i];
#pragma unroll
      for (int j = 0; j < TN; j += 4) *(float4*)&b[j] = *(const float4*)&Bs[kk][tn + j];
#pragma unroll
      for (int i = 0; i < TM; ++i)
#pragma unroll
        for (int j = 0; j < TN; ++j) acc[i][j] = fmaf(a[i], b[j], acc[i][j]);
    }
    __syncthreads();
  }

#pragma unroll
  for (int i = 0; i < TM; ++i) {
    const int m = m0 + tm + i;
    const int b = m >> 11, l = m & (L_ - 1);
#pragma unroll
    for (int j = 0; j < TN; ++j) {
      const int n = n0 + tn + j;
      float v = acc[i][j] + bias[n];
      const int which = n >> 9, h = (n >> 6) & (NH_ - 1), d = n & (HD_ - 1);
      const int bh = b * NH_ + h;
      if (which == 0) {
        v *= 0.125f;                        // fold attention scale into Q
        ushort_t hi = bfrne(v);
        float hf = __uint_as_float((unsigned)hi << 16);
        ushort_t lo = bfrne(v - hf);
        const size_t o = ((size_t)bh * L_ + l) * HD_ + d;
        Qh[o] = hi; Ql[o] = lo;
      } else if (which == 1) {
        ushort_t hi = bfrne(v);
        float hf = __uint_as_float((unsigned)hi << 16);
        ushort_t lo = bfrne(v - hf);
        const size_t o = ((size_t)bh * L_ + l) * HD_ + d;
        Kh[o] = hi; Kl[o] = lo;
      } else {
        Vt[((size_t)bh * HD_ + d) * L_ + l] = bfrne(v);
      }
    }
  }
}

// ---------------- out = AO @ w_out^T + b (f32 VALU GEMM) ----------------
__global__ __launch_bounds__(256) void gemm_out(
    const float* __restrict__ A, const float* __restrict__ Bw,
    const float* __restrict__ bias, float* __restrict__ out)
{
  constexpr int BM = 64, BN = 64, BK = 16, TM = 4, TN = 4;
  const int N = DIM_, K = DIM_;
  __shared__ float As[BK][BM];
  __shared__ float Bs[BK][BN];
  const int tid = threadIdx.x;
  const int m0 = blockIdx.y * BM;
  const int n0 = blockIdx.x * BN;
  constexpr int TX = BN / TN;
  const int tn = (tid % TX) * TN;
  const int tm = (tid / TX) * TM;

  float acc[TM][TN];
#pragma unroll
  for (int i = 0; i < TM; ++i)
#pragma unroll
    for (int j = 0; j < TN; ++j) acc[i][j] = 0.f;

  constexpr int A4 = BM * BK / 4;
  constexpr int B4 = BN * BK / 4;

  for (int k0 = 0; k0 < K; k0 += BK) {
    for (int idx = tid; idx < A4; idx += 256) {
      int e = idx * 4;
      int row = e / BK, col = e % BK;
      float4 v = *(const float4*)(A + (size_t)(m0 + row) * K + k0 + col);
      As[col][row] = v.x; As[col+1][row] = v.y; As[col+2][row] = v.z; As[col+3][row] = v.w;
    }
    for (int idx = tid; idx < B4; idx += 256) {
      int e = idx * 4;
      int row = e / BK, col = e % BK;
      float4 v = *(const float4*)(Bw + (size_t)(n0 + row) * K + k0 + col);
      Bs[col][row] = v.x; Bs[col+1][row] = v.y; Bs[col+2][row] = v.z; Bs[col+3][row] = v.w;
    }
    __syncthreads();
#pragma unroll
    for (int kk = 0; kk < BK; ++kk) {
      float a[TM], b[TN];
#pragma unroll
      for (int i = 0; i < TM; i += 4) *(float4*)&a[i] = *(const float4*)&As[kk][tm + i];
#pragma unroll
      for (int j = 0; j < TN; j += 4) *(float4*)&b[j] = *(const float4*)&Bs[kk][tn + j];
#pragma unroll
      for (int i = 0; i < TM; ++i)
#pragma unroll
        for (int j = 0; j < TN; ++j) acc[i][j] = fmaf(a[i], b[j], acc[i][j]);
    }
    __syncthreads();
  }

#pragma unroll
  for (int i = 0; i < TM; ++i) {
    const int m = m0 + tm + i;
#pragma unroll
    for (int j = 0; j < TN; ++j)
      out[(size_t)m * N + n0 + tn + j] = acc[i][j] + bias[n0 + tn + j];
  }
}

// ---------------- Attention: 1 block = 16 query rows of one (b,h) ----------------
// 1024 threads = 16 waves. Phase 1: bf16x3 MFMA scores -> LDS (f32, ~3e-5 exact).
// Phase 2: per-wave exact top-512 (24-bit bisection) -> dense P row in place.
// Phase 3: dense P(16x2048) @ V(2048x64) via MFMA, cross-wave LDS reduction.
__global__ __launch_bounds__(1024, 1) void attn_k(
    const ushort_t* __restrict__ Qh, const ushort_t* __restrict__ Ql,
    const ushort_t* __restrict__ Kh, const ushort_t* __restrict__ Kl,
    const ushort_t* __restrict__ Vt, float* __restrict__ AO)
{
  __shared__ float sc[16][2052];   // 128.3 KiB: scores -> dense P -> reduce buffer
  __shared__ float invs[16];

  const int tid = threadIdx.x, lane = tid & 63, wid = tid >> 6;   // 16 waves
  const int bh = blockIdx.x >> 7;           // 128 blocks per bh
  const int l0 = (blockIdx.x & 127) << 4;   // 16 rows per block
  const int arow = lane & 15, agrp = lane >> 4;

  // Q A-fragments (rows l0..l0+15), loaded by every wave (cheap)
  const size_t qbase = ((size_t)bh * L_ + l0 + arow) * HD_ + agrp * 8;
  const short8 qh0 = *(const short8*)(Qh + qbase);
  const short8 qh1 = *(const short8*)(Qh + qbase + 32);
  const short8 ql0 = *(const short8*)(Ql + qbase);
  const short8 ql1 = *(const short8*)(Ql + qbase + 32);

  // ---- Phase 1: scores. Wave wid owns keys [wid*128, wid*128+128) ----
  {
    const int key00 = wid << 7;
#pragma unroll
    for (int t = 0; t < 8; ++t) {
      const int key0 = key00 + t * 16;
      const size_t ka = ((size_t)bh * L_ + key0 + arow) * HD_ + agrp * 8;
      const short8 kh0 = *(const short8*)(Kh + ka);
      const short8 kh1 = *(const short8*)(Kh + ka + 32);
      const short8 kl0 = *(const short8*)(Kl + ka);
      const short8 kl1 = *(const short8*)(Kl + ka + 32);
      f32x4 acc = {0.f, 0.f, 0.f, 0.f};
      acc = __builtin_amdgcn_mfma_f32_16x16x32_bf16(qh0, kh0, acc, 0, 0, 0);
      acc = __builtin_amdgcn_mfma_f32_16x16x32_bf16(qh1, kh1, acc, 0, 0, 0);
      acc = __builtin_amdgcn_mfma_f32_16x16x32_bf16(ql0, kh0, acc, 0, 0, 0);
      acc = __builtin_amdgcn_mfma_f32_16x16x32_bf16(ql1, kh1, acc, 0, 0, 0);
      acc = __builtin_amdgcn_mfma_f32_16x16x32_bf16(qh0, kl0, acc, 0, 0, 0);
      acc = __builtin_amdgcn_mfma_f32_16x16x32_bf16(qh1, kl1, acc, 0, 0, 0);
      // C layout: col(key) = lane&15, row(q) = (lane>>4)*4 + reg  [HW-verified]
#pragma unroll
      for (int rr = 0; rr < 4; ++rr) sc[agrp * 4 + rr][key0 + arow] = acc[rr];
    }
  }
  __syncthreads();

  // ---- Phase 2: exact top-512 selection, row = wid; dense P written in place ----
  {
    const int r = wid;
    unsigned keys[32];
    float mx = -3.0e38f;
#pragma unroll
    for (int t = 0; t < 32; ++t) {
      const float s = sc[r][lane + 64 * t];
      keys[t] = f2ord(s);
      mx = fmaxf(mx, s);
    }
#pragma unroll
    for (int off = 32; off; off >>= 1) mx = fmaxf(mx, __shfl_xor(mx, off));

    unsigned P = 0;
#pragma unroll 1
    for (int bit = 31; bit >= 8; --bit) {   // 24 bits: 2^8-ulp ties < score noise
      const unsigned cand = P | (1u << bit);
      int c = 0;
#pragma unroll
      for (int t = 0; t < 32; ++t)
        c += (int)__popcll(__ballot(keys[t] >= cand));
      if (c >= TOPK_) P = cand;
    }

    int base = 0;
    float part = 0.f;
#pragma unroll
    for (int t = 0; t < 32; ++t) {
      const bool sel = keys[t] >= P;
      const unsigned long long mb = __ballot(sel);
      const int pos = base + (int)__popcll(mb & ((1ull << lane) - 1ull));
      const float p = (sel && pos < TOPK_) ? __expf(ord2f(keys[t]) - mx) : 0.f;
      sc[r][lane + 64 * t] = p;             // dense P (0 where unselected)
      part += p;
      base += (int)__popcll(mb);
    }
#pragma unroll
    for (int off = 32; off; off >>= 1) part += __shfl_xor(part, off);
    if (lane == 0) invs[r] = 1.f / part;
  }
  __syncthreads();

  // ---- Phase 3: PV = P(16x2048) @ V(2048x64); wave wid does keys [wid*128,+128) ----
  f32x4 o0 = {0.f,0.f,0.f,0.f}, o1 = o0, o2 = o0, o3 = o0;
  {
    const int key00 = wid << 7;
#pragma unroll
    for (int ks = 0; ks < 4; ++ks) {
      const int kb = key00 + ks * 32 + agrp * 8;
      float pf[8];
      *(float4*)&pf[0] = *(const float4*)&sc[arow][kb];
      *(float4*)&pf[4] = *(const float4*)&sc[arow][kb + 4];
      short8 pa;
#pragma unroll
      for (int j = 0; j < 8; ++j) pa[j] = (short)bfrne(pf[j]);
      const size_t vb0 = ((size_t)bh * HD_ + arow) * L_ + kb;
      const short8 v0 = *(const short8*)(Vt + vb0);
      const short8 v1 = *(const short8*)(Vt + vb0 + 16 * L_);
      const short8 v2 = *(const short8*)(Vt + vb0 + 32 * L_);
      const short8 v3 = *(const short8*)(Vt + vb0 + 48 * L_);
      o0 = __builtin_amdgcn_mfma_f32_16x16x32_bf16(pa, v0, o0, 0, 0, 0);
      o1 = __builtin_amdgcn_mfma_f32_16x16x32_bf16(pa, v1, o1, 0, 0, 0);
      o2 = __builtin_amdgcn_mfma_f32_16x16x32_bf16(pa, v2, o2, 0, 0, 0);
      o3 = __builtin_amdgcn_mfma_f32_16x16x32_bf16(pa, v3, o3, 0, 0, 0);
    }
  }
  __syncthreads();                 // all P reads done; sc reusable

  // ---- cross-wave reduction of 16 partial Out(16x64) tiles ----
  float* red = &sc[0][0];          // [16][16][64] f32 = 64 KiB
  {
#pragma unroll
    for (int rr = 0; rr < 4; ++rr) {
      const int row = agrp * 4 + rr;
      red[wid * 1024 + row * 64 +  0 + arow] = o0[rr];
      red[wid * 1024 + row * 64 + 16 + arow] = o1[rr];
      red[wid * 1024 + row * 64 + 32 + arow] = o2[rr];
      red[wid * 1024 + row * 64 + 48 + arow] = o3[rr];
    }
  }
  __syncthreads();
  {
    const int b = bh >> 3, h = bh & 7;
    const int r = tid >> 6, d = tid & 63;
    float s = 0.f;
#pragma unroll
    for (int w = 0; w < 16; ++w) s += red[w * 1024 + tid];
    AO[((size_t)(b * L_ + l0 + r)) * DIM_ + h * HD_ + d] = s * invs[r];
  }
}

extern "C" void kernel_launch(void* const* d_in, const int* in_sizes, int n_in,
                              void* d_out, int out_size, void* d_ws, size_t ws_size,
                              hipStream_t stream) {
  const float* x     = (const float*)d_in[0];
  const float* w_qkv = (const float*)d_in[1];
  const float* b_qkv = (const float*)d_in[2];
  const float* w_out = (const float*)d_in[3];
  const float* b_out = (const float*)d_in[4];
  float* out = (float*)d_out;

  const size_t NE = (size_t)B_ * NH_ * L_ * HD_;   // 2,097,152
  ushort_t* Qh = (ushort_t*)d_ws;
  ushort_t* Ql = Qh + NE;
  ushort_t* Kh = Ql + NE;
  ushort_t* Kl = Kh + NE;
  ushort_t* Vt = Kl + NE;
  float*    AO = (float*)(Vt + NE);                // [b][l][512] f32, 8 MB
  const int M = B_ * L_;                           // 4096

  gemm_qkv<<<dim3((3 * DIM_) / 128, M / 128), 256, 0, stream>>>(
      x, w_qkv, b_qkv, Qh, Ql, Kh, Kl, Vt);
  attn_k<<<dim3(B_ * NH_ * (L_ / 16)), 1024, 0, stream>>>(Qh, Ql, Kh, Kl, Vt, AO);
  gemm_out<<<dim3(DIM_ / 64, M / 64), 256, 0, stream>>>(AO, w_out, b_out, out);
}